// Round 2
// baseline (175.673 us; speedup 1.0000x reference)
//
#include <hip/hip_runtime.h>
#include <math.h>

// Problem constants (B,N,D)=(8,2048,256), S=128, H=512, E=2H+S=1152
#define BB 8
#define NN 2048
#define DD 256
#define SS 128
#define HH 512
#define EE 1152

typedef short bf16x8 __attribute__((ext_vector_type(8)));
typedef float f32x4 __attribute__((ext_vector_type(4)));

__device__ __forceinline__ short f2bf(float f) {
    union { float f; unsigned u; } a; a.f = f;
    unsigned r = a.u + 0x7FFFu + ((a.u >> 16) & 1u);  // RNE
    return (short)(r >> 16);
}
__device__ __forceinline__ float bf2f(short s) {
    union { unsigned u; float f; } a; a.u = ((unsigned)(unsigned short)s) << 16;
    return a.f;
}
// async global->LDS, 16B per lane; lds dest = wave-uniform base + lane*16
__device__ __forceinline__ void gl_lds16(const short* g, short* l) {
    __builtin_amdgcn_global_load_lds(
        (const __attribute__((address_space(1))) void*)g,
        (__attribute__((address_space(3))) void*)l, 16, 0, 0);
}

// ---------------- K1: fused RMS norm + weight prep (one launch) ------------
__global__ __launch_bounds__(256) void k_pre(
        const float* __restrict__ x, const float* __restrict__ gp,
        short* __restrict__ xn,
        const float* __restrict__ Wuv, const float* __restrict__ Wo,
        short* __restrict__ Wuv_t, short* __restrict__ Wo_t) {
    __shared__ float tile[32][33];
    int bid = blockIdx.x;
    int t = threadIdx.x;
    if (bid < 4096) {
        int wave = t >> 6, lane = t & 63;
        long row = (long)bid * 4 + wave;
        float4 xv = ((const float4*)(x + row * DD))[lane];
        float ss = xv.x*xv.x + xv.y*xv.y + xv.z*xv.z + xv.w*xv.w;
        #pragma unroll
        for (int off = 32; off > 0; off >>= 1) ss += __shfl_down(ss, off);
        ss = __shfl(ss, 0);
        float norm = sqrtf(ss) * 0.0625f;              // ||x|| / sqrt(256)
        float scale = gp[0] / fmaxf(norm, 1e-5f);
        short4 o;
        o.x = f2bf(xv.x * scale); o.y = f2bf(xv.y * scale);
        o.z = f2bf(xv.z * scale); o.w = f2bf(xv.w * scale);
        ((short4*)(xn + row * DD))[lane] = o;
    } else if (bid < 4384) {
        int bid2 = bid - 4096;                // 36 e-tiles x 8 d-tiles
        int et = bid2 % 36, dt = bid2 / 36;
        #pragma unroll
        for (int i = 0; i < 4; i++) {
            int idx = t + i*256, r = idx >> 5, c = idx & 31;
            tile[r][c] = Wuv[(long)(dt*32 + r)*EE + et*32 + c];
        }
        __syncthreads();
        #pragma unroll
        for (int i = 0; i < 4; i++) {
            int idx = t + i*256, r = idx >> 5, c = idx & 31;
            Wuv_t[(long)(et*32 + r)*DD + dt*32 + c] = f2bf(tile[c][r]);
        }
    } else {
        int bid3 = bid - 4384;                // 16 h-tiles x 8 d-tiles
        int ht = bid3 % 16, dt = bid3 / 16;
        #pragma unroll
        for (int i = 0; i < 4; i++) {
            int idx = t + i*256, r = idx >> 5, c = idx & 31;
            tile[r][c] = Wo[(long)(ht*32 + r)*DD + dt*32 + c];
        }
        __syncthreads();
        #pragma unroll
        for (int i = 0; i < 4; i++) {
            int idx = t + i*256, r = idx >> 5, c = idx & 31;
            Wo_t[(long)(dt*32 + r)*HH + ht*32 + c] = f2bf(tile[c][r]);
        }
    }
}

// ---------------- K3: GEMM1 + silu + split epilogue (v3) --------------------
// 128x128 tile, 4 waves, BK=32, 3-buffer depth-2 pipeline with counted
// vmcnt(4) + raw s_barrier (T3/T4): stage(ks+2) issued AFTER the barrier
// (WAR-safe: buf[(ks+2)%3] was last read at iter ks-1, all waves past it).
// LDS tile layout is XOR-swizzled (2-row-pair, (rp&7)<<4) so b128 frag reads
// are at the 2-way bank floor; gl_lds keeps LDS linear, so the SOURCE global
// address is pre-swizzled per lane (rule #21 / m173 pattern).
// off_bytes(row,cb) = (row>>1)*128 + (((row&1)*64 + cb) ^ (((row>>1)&7)<<4))
#define GOFF(row,cbb) ((((row)>>1)*64) + \
    (((((row)&1)*64 + (cbb)) ^ ((((row)>>1)&7)<<4)) >> 1))

__global__ __launch_bounds__(256, 3) void k_gemm1(
        const short* __restrict__ xn, const short* __restrict__ Wuv_t,
        const float* __restrict__ b_uv,
        const float* __restrict__ gamma, const float* __restrict__ beta,
        short* __restrict__ u, short* __restrict__ vfrag,
        short* __restrict__ q, short* __restrict__ k) {
    __shared__ short As[3][128*32];
    __shared__ short Bs[3][128*32];
    int m0 = blockIdx.x * 128, n0 = blockIdx.y * 128;
    int t = threadIdx.x, w = t >> 6, lane = t & 63;
    int wr = w & 1, wc = w >> 1, l16 = lane & 15, quad = lane >> 4;
    // staging source pre-swizzle: lane's linear LDS slot (16 rows x 64B per
    // inst) holds global element (srow, scb) under the swizzled layout.
    int sql  = (((lane & 7) ^ (lane >> 3)) * 16);   // byte offset in 128B pair
    int srow = ((lane >> 3) * 2) + (sql >> 6);      // row offset 0..15
    int scb  = (sql & 63) >> 1;                     // shorts: 0,8,16,24
    f32x4 acc[4][4] = {};
    // prologue: stage K-steps 0 and 1
    #pragma unroll
    for (int ps = 0; ps < 2; ps++) {
        #pragma unroll
        for (int i = 0; i < 2; i++) {
            int r0 = i*64 + w*16;
            gl_lds16(&xn[(long)(m0 + r0 + srow)*DD + ps*32 + scb], &As[ps][r0*32]);
            gl_lds16(&Wuv_t[(long)(n0 + r0 + srow)*DD + ps*32 + scb], &Bs[ps][r0*32]);
        }
    }
    for (int ks = 0; ks < 8; ks++) {
        int cur = ks - (ks/3)*3;                   // ks % 3
        if (ks < 7) asm volatile("s_waitcnt vmcnt(4)" ::: "memory");
        else        asm volatile("s_waitcnt vmcnt(0)" ::: "memory");
        __builtin_amdgcn_s_barrier();
        if (ks + 2 < 8) {                          // depth-2 prefetch
            int nb = (ks+2) - ((ks+2)/3)*3;
            int k0 = (ks+2)*32;
            #pragma unroll
            for (int i = 0; i < 2; i++) {
                int r0 = i*64 + w*16;
                gl_lds16(&xn[(long)(m0 + r0 + srow)*DD + k0 + scb], &As[nb][r0*32]);
                gl_lds16(&Wuv_t[(long)(n0 + r0 + srow)*DD + k0 + scb], &Bs[nb][r0*32]);
            }
        }
        bf16x8 a[4], bb[4];
        #pragma unroll
        for (int mt = 0; mt < 4; mt++)
            a[mt] = *(const bf16x8*)&As[cur][GOFF(wr*64 + mt*16 + l16, quad*16)];
        #pragma unroll
        for (int nt = 0; nt < 4; nt++)
            bb[nt] = *(const bf16x8*)&Bs[cur][GOFF(wc*64 + nt*16 + l16, quad*16)];
        #pragma unroll
        for (int mt = 0; mt < 4; mt++)
            #pragma unroll
            for (int nt = 0; nt < 4; nt++)
                acc[mt][nt] = __builtin_amdgcn_mfma_f32_16x16x32_bf16(
                    a[mt], bb[nt], acc[mt][nt], 0,0,0);
    }
    #pragma unroll
    for (int mt = 0; mt < 4; mt++)
    #pragma unroll
    for (int nt = 0; nt < 4; nt++) {
        int gm0 = m0 + wr*64 + mt*16 + quad*4;        // rows gm0..gm0+3
        int ge  = n0 + wc*64 + nt*16 + l16;
        float val[4];
        #pragma unroll
        for (int r = 0; r < 4; r++) {
            float xv = acc[mt][nt][r] + b_uv[ge];
            val[r] = xv / (1.0f + __expf(-xv));        // silu
        }
        if (ge < HH) {
            #pragma unroll
            for (int r = 0; r < 4; r++)
                u[(long)(gm0 + r)*HH + ge] = f2bf(val[r]);
        } else if (ge < 2*HH) {
            int h = ge - HH;
            // vfrag addr: ((b*64+mt32)*32 + ht)*512 + lane'*8 + e
            long base = (((long)((gm0 >> 11)*64 + ((gm0 & 2047) >> 5)) * 32)
                         + (h >> 4)) * 512
                        + ((((gm0 & 31) >> 3)*16 + (h & 15)) * 8) + (gm0 & 7);
            short4 o;
            o.x = f2bf(val[0]); o.y = f2bf(val[1]);
            o.z = f2bf(val[2]); o.w = f2bf(val[3]);
            *(short4*)&vfrag[base] = o;
        } else {
            int si = ge - 2*HH;
            #pragma unroll
            for (int r = 0; r < 4; r++) {
                q[(long)(gm0 + r)*SS + si] = f2bf(val[r] * gamma[si]      + beta[si]);
                k[(long)(gm0 + r)*SS + si] = f2bf(val[r] * gamma[SS + si] + beta[SS + si]);
            }
        }
    }
}

// ---------------- K5: attention + u-gate + fused GEMM2 (v9) ----------------
// v9 vs v8:
//  - full-strength XOR swizzles ((row&15)<<4 on 256B/1024B rows, (row&7)<<4
//    on 128B rows): every b128 frag read/write at the 2-way bank floor
//    (v8's (row&3) swizzle only gave a 4-way spread -> 9.2M conflicts).
//  - PV split by (h-group x qq-half): wave = (hg=w&7 -> 64 h-cols,
//    qh=w>>3 -> q-tiles {2qh,2qh+1}). Each wave reads only HALF of P
//    (4 b128 vs 8) -> P LDS-read traffic halved (128->64 KB/iter/CU).
//    QK mapping (qt=w>>2, mtile=w&3) unchanged; MFMA totals unchanged.
// Hazard structure IDENTICAL to proven v4/v7/v8 single-barrier scheme.
// LDS (shorts): ks[2][64][128] swz @0 (16384), Ps[2][64][64] swz @16384
// (8192); epilogue overlay GT[64][512] swz @0 (32768). dynamic = 65536 B.
#define KSW(pp,row,cb) (smem + ((pp)*64 + (row))*128 + \
    ((((cb) ^ (((row)&15)<<4))) >> 1))
#define PSW(pp,row,cb) (smem + 16384 + ((pp)*64 + (row))*64 + \
    ((((cb) ^ (((row)&7)<<4))) >> 1))
#define GTW(row,cb)    (smem + (row)*512 + ((((cb) ^ (((row)&15)<<4))) >> 1))

__global__ __launch_bounds__(1024, 4) void k_attn(
        const short* __restrict__ q, const short* __restrict__ k,
        const short* __restrict__ vfrag, const short* __restrict__ u,
        const short* __restrict__ Wo_t, const float* __restrict__ b_o,
        float* __restrict__ out) {
    extern __shared__ __align__(16) short smem[];
    int b = blockIdx.x & 7;                  // batch -> XCD pin
    int i0 = (blockIdx.x >> 3) * 64;
    int t = threadIdx.x, w = t >> 6, lane = t & 63;
    int l16 = lane & 15, quad = lane >> 4;
    int qt = w >> 2, mtile = w & 3;          // QK tile assignment (4x4)
    int hg = w & 7, qh = w >> 3;             // PV assignment: 64 h-cols, 2 q-tiles
    const short* qb  = q + ((long)b * NN + i0) * SS;
    const short* kb  = k + (long)b * NN * SS;
    const short* vfb = vfrag + (long)b * 64 * 32 * 512;
    const float RS = 0.08838834764831845f;   // 1/sqrt(128)

    int krow = t >> 4, kch = t & 15;         // k staging: 64 rows x 16 chunks(16B)

    // hoist q B-frags for this wave's q-tile: B[n=q=l16][k=s]
    bf16x8 qf[4];
    #pragma unroll
    for (int kc = 0; kc < 4; kc++)
        qf[kc] = *(const bf16x8*)&qb[(long)(qt*16 + l16)*SS + kc*32 + quad*8];

    // prologue: stage k rows 0..63 -> ks[0]; preload rows 64..127 -> kpre
    *(bf16x8*)KSW(0, krow, kch*16) = *(const bf16x8*)&kb[(long)krow*SS + kch*8];
    bf16x8 kpre = *(const bf16x8*)&kb[(long)(64 + krow)*SS + kch*8];
    __syncthreads();

    f32x4 acc[2][4] = {};
    for (int it = 0; it < NN/64; it++) {
        int p = it & 1;
        int m0 = it * 64;
        // preload k for m0+128 (clamp keeps address valid; value unused at end)
        int mnext = (m0 + 128 < NN) ? m0 + 128 : m0;
        bf16x8 knext = *(const bf16x8*)&kb[(long)(mnext + krow)*SS + kch*8];
        // this iter's v B-frags: coalesced 1KB global loads (land during QK)
        bf16x8 vf[2][4];
        #pragma unroll
        for (int s = 0; s < 2; s++)
            #pragma unroll
            for (int j = 0; j < 4; j++)
                vf[s][j] = *(const bf16x8*)
                    &vfb[((long)(it*2 + s)*32 + (hg*4 + j))*512 + lane*8];
        // QK: S^T tile (16m x 16q), A = k-frags from swizzled LDS, B = q regs
        f32x4 sc = {};
        #pragma unroll
        for (int kc = 0; kc < 4; kc++) {
            bf16x8 kf = *(const bf16x8*)KSW(p, mtile*16 + l16, kc*64 + quad*16);
            sc = __builtin_amdgcn_mfma_f32_16x16x32_bf16(kf, qf[kc], sc, 0,0,0);
        }
        short4 pw;
        {
            float s0 = fmaxf(sc[0]*RS, 0.f), s1 = fmaxf(sc[1]*RS, 0.f);
            float s2 = fmaxf(sc[2]*RS, 0.f), s3 = fmaxf(sc[3]*RS, 0.f);
            pw.x = f2bf(s0*s0); pw.y = f2bf(s1*s1);
            pw.z = f2bf(s2*s2); pw.w = f2bf(s3*s3);
        }
        // C-layout: row m = quad*4+r, col q = l16 -> store P^T[q][m]
        *(short4*)PSW(p, qt*16 + l16, mtile*32 + quad*8) = pw;
        // stage k(m0+64) into the other buffer (loaded last iter, landed)
        *(bf16x8*)KSW(p^1, krow, kch*16) = kpre;
        kpre = knext;
        __syncthreads();                       // single barrier per iter
        // PV: A-frags = this wave's 2 q-tiles of Ps[p]; B = vf in regs
        __builtin_amdgcn_s_setprio(1);
        #pragma unroll
        for (int s = 0; s < 2; s++) {
            bf16x8 af[2];
            #pragma unroll
            for (int q2 = 0; q2 < 2; q2++)
                af[q2] = *(const bf16x8*)PSW(p, (qh*2 + q2)*16 + l16,
                                             s*64 + quad*16);
            #pragma unroll
            for (int q2 = 0; q2 < 2; q2++)
                #pragma unroll
                for (int j = 0; j < 4; j++)
                    acc[q2][j] = __builtin_amdgcn_mfma_f32_16x16x32_bf16(
                        af[q2], vf[s][j], acc[q2][j], 0,0,0);
        }
        __builtin_amdgcn_s_setprio(0);
    }

    // ---- fused GEMM2 epilogue: out[64 x 256] = (u .* PV) @ Wo + b_o ----
    // acc C-layout: q = (qh*2+q2)*16 + quad*4 + r, h = hg*64 + j*16 + l16.
    long rowbase = (long)b * NN + i0;
    __syncthreads();                         // B1: all main-loop LDS ops dead
    #pragma unroll
    for (int q2 = 0; q2 < 2; q2++)
    #pragma unroll
    for (int j = 0; j < 4; j++) {
        int gh = hg*64 + j*16 + l16;
        #pragma unroll
        for (int r = 0; r < 4; r++) {
            int row = (qh*2 + q2)*16 + quad*4 + r;
            float uval = bf2f(u[(rowbase + row)*HH + gh]);
            *GTW(row, 2*gh) = f2bf(acc[q2][j][r] * uval);
        }
    }
    __syncthreads();                         // B2: writes visible; reads only below
    f32x4 acc2[4] = {};
    #pragma unroll
    for (int kc = 0; kc < 16; kc++) {        // K = 512 in 32-chunks
        bf16x8 A[4];
        #pragma unroll
        for (int qq = 0; qq < 4; qq++)
            A[qq] = *(const bf16x8*)GTW(qq*16 + l16, kc*64 + quad*16);
        bf16x8 Bf = *(const bf16x8*)&Wo_t[(long)(w*16 + l16)*HH + kc*32 + quad*8];
        #pragma unroll
        for (int qq = 0; qq < 4; qq++)
            acc2[qq] = __builtin_amdgcn_mfma_f32_16x16x32_bf16(A[qq], Bf, acc2[qq], 0,0,0);
    }
    // store out + bias (fp32); wave w owns d-cols [w*16, w*16+16)
    #pragma unroll
    for (int qq = 0; qq < 4; qq++)
    #pragma unroll
    for (int r = 0; r < 4; r++) {
        long grow = rowbase + qq*16 + quad*4 + r;
        int gd = w*16 + l16;
        out[grow*DD + gd] = acc2[qq][r] + b_o[gd];
    }
}

extern "C" void kernel_launch(void* const* d_in, const int* in_sizes, int n_in,
                              void* d_out, int out_size, void* d_ws, size_t ws_size,
                              hipStream_t stream) {
    const float* x     = (const float*)d_in[0];
    const float* g     = (const float*)d_in[1];
    const float* Wuv   = (const float*)d_in[2];
    const float* b_uv  = (const float*)d_in[3];
    const float* gamma = (const float*)d_in[4];
    const float* beta  = (const float*)d_in[5];
    const float* Wo    = (const float*)d_in[6];
    const float* b_o   = (const float*)d_in[7];
    float* out = (float*)d_out;

    short* ws    = (short*)d_ws;
    short* xn    = ws;                                  // 16384*256
    short* Wuv_t = xn    + (long)16384 * 256;           // 1152*256
    short* Wo_t  = Wuv_t + (long)1152 * 256;            // 256*512
    short* u     = Wo_t  + (long)256 * 512;             // 16384*512
    short* vfrag = u     + (long)16384 * 512;           // 16384*512 (frag layout)
    short* qq    = vfrag + (long)16384 * 512;           // 16384*128
    short* kk    = qq    + (long)16384 * 128;           // 16384*128

    k_pre<<<4512, 256, 0, stream>>>(x, g, xn, Wuv, Wo, Wuv_t, Wo_t);
    k_gemm1<<<dim3(128, 9), 256, 0, stream>>>(xn, Wuv_t, b_uv, gamma, beta,
                                              u, vfrag, qq, kk);
    k_attn<<<256, 1024, 65536, stream>>>(qq, kk, vfrag, u, Wo_t, b_o, out);
}

// Round 3
// 166.250 us; speedup vs baseline: 1.0567x; 1.0567x over previous
//
#include <hip/hip_runtime.h>
#include <math.h>

// Problem constants (B,N,D)=(8,2048,256), S=128, H=512, E=2H+S=1152
#define BB 8
#define NN 2048
#define DD 256
#define SS 128
#define HH 512
#define EE 1152

typedef short bf16x8 __attribute__((ext_vector_type(8)));
typedef float f32x4 __attribute__((ext_vector_type(4)));

__device__ __forceinline__ short f2bf(float f) {
    union { float f; unsigned u; } a; a.f = f;
    unsigned r = a.u + 0x7FFFu + ((a.u >> 16) & 1u);  // RNE
    return (short)(r >> 16);
}
__device__ __forceinline__ float bf2f(short s) {
    union { unsigned u; float f; } a; a.u = ((unsigned)(unsigned short)s) << 16;
    return a.f;
}
// async global->LDS, 16B per lane; lds dest = wave-uniform base + lane*16
__device__ __forceinline__ void gl_lds16(const short* g, short* l) {
    __builtin_amdgcn_global_load_lds(
        (const __attribute__((address_space(1))) void*)g,
        (__attribute__((address_space(3))) void*)l, 16, 0, 0);
}

// ---------------- K1: fused RMS norm + weight prep (one launch) ------------
__global__ __launch_bounds__(256) void k_pre(
        const float* __restrict__ x, const float* __restrict__ gp,
        short* __restrict__ xn,
        const float* __restrict__ Wuv, const float* __restrict__ Wo,
        short* __restrict__ Wuv_t, short* __restrict__ Wo_t) {
    __shared__ float tile[32][33];
    int bid = blockIdx.x;
    int t = threadIdx.x;
    if (bid < 4096) {
        int wave = t >> 6, lane = t & 63;
        long row = (long)bid * 4 + wave;
        float4 xv = ((const float4*)(x + row * DD))[lane];
        float ss = xv.x*xv.x + xv.y*xv.y + xv.z*xv.z + xv.w*xv.w;
        #pragma unroll
        for (int off = 32; off > 0; off >>= 1) ss += __shfl_down(ss, off);
        ss = __shfl(ss, 0);
        float norm = sqrtf(ss) * 0.0625f;              // ||x|| / sqrt(256)
        float scale = gp[0] / fmaxf(norm, 1e-5f);
        short4 o;
        o.x = f2bf(xv.x * scale); o.y = f2bf(xv.y * scale);
        o.z = f2bf(xv.z * scale); o.w = f2bf(xv.w * scale);
        ((short4*)(xn + row * DD))[lane] = o;
    } else if (bid < 4384) {
        int bid2 = bid - 4096;                // 36 e-tiles x 8 d-tiles
        int et = bid2 % 36, dt = bid2 / 36;
        #pragma unroll
        for (int i = 0; i < 4; i++) {
            int idx = t + i*256, r = idx >> 5, c = idx & 31;
            tile[r][c] = Wuv[(long)(dt*32 + r)*EE + et*32 + c];
        }
        __syncthreads();
        #pragma unroll
        for (int i = 0; i < 4; i++) {
            int idx = t + i*256, r = idx >> 5, c = idx & 31;
            Wuv_t[(long)(et*32 + r)*DD + dt*32 + c] = f2bf(tile[c][r]);
        }
    } else {
        int bid3 = bid - 4384;                // 16 h-tiles x 8 d-tiles
        int ht = bid3 % 16, dt = bid3 / 16;
        #pragma unroll
        for (int i = 0; i < 4; i++) {
            int idx = t + i*256, r = idx >> 5, c = idx & 31;
            tile[r][c] = Wo[(long)(ht*32 + r)*DD + dt*32 + c];
        }
        __syncthreads();
        #pragma unroll
        for (int i = 0; i < 4; i++) {
            int idx = t + i*256, r = idx >> 5, c = idx & 31;
            Wo_t[(long)(dt*32 + r)*HH + ht*32 + c] = f2bf(tile[c][r]);
        }
    }
}

// ---------------- K3: GEMM1 + silu + split epilogue (v3) --------------------
// 128x128 tile, 4 waves, BK=32, 3-buffer depth-2 pipeline with counted
// vmcnt(4) + raw s_barrier (T3/T4): stage(ks+2) issued AFTER the barrier
// (WAR-safe). Pre-swizzled global source + swizzled frag reads (rule #21).
#define GOFF(row,cbb) ((((row)>>1)*64) + \
    (((((row)&1)*64 + (cbb)) ^ ((((row)>>1)&7)<<4)) >> 1))

__global__ __launch_bounds__(256, 3) void k_gemm1(
        const short* __restrict__ xn, const short* __restrict__ Wuv_t,
        const float* __restrict__ b_uv,
        const float* __restrict__ gamma, const float* __restrict__ beta,
        short* __restrict__ u, short* __restrict__ vfrag,
        short* __restrict__ q, short* __restrict__ k) {
    __shared__ short As[3][128*32];
    __shared__ short Bs[3][128*32];
    int m0 = blockIdx.x * 128, n0 = blockIdx.y * 128;
    int t = threadIdx.x, w = t >> 6, lane = t & 63;
    int wr = w & 1, wc = w >> 1, l16 = lane & 15, quad = lane >> 4;
    // staging source pre-swizzle: lane's linear LDS slot (16 rows x 64B per
    // inst) holds global element (srow, scb) under the swizzled layout.
    int sql  = (((lane & 7) ^ (lane >> 3)) * 16);   // byte offset in 128B pair
    int srow = ((lane >> 3) * 2) + (sql >> 6);      // row offset 0..15
    int scb  = (sql & 63) >> 1;                     // shorts: 0,8,16,24
    f32x4 acc[4][4] = {};
    // prologue: stage K-steps 0 and 1
    #pragma unroll
    for (int ps = 0; ps < 2; ps++) {
        #pragma unroll
        for (int i = 0; i < 2; i++) {
            int r0 = i*64 + w*16;
            gl_lds16(&xn[(long)(m0 + r0 + srow)*DD + ps*32 + scb], &As[ps][r0*32]);
            gl_lds16(&Wuv_t[(long)(n0 + r0 + srow)*DD + ps*32 + scb], &Bs[ps][r0*32]);
        }
    }
    for (int ks = 0; ks < 8; ks++) {
        int cur = ks - (ks/3)*3;                   // ks % 3
        if (ks < 7) asm volatile("s_waitcnt vmcnt(4)" ::: "memory");
        else        asm volatile("s_waitcnt vmcnt(0)" ::: "memory");
        __builtin_amdgcn_s_barrier();
        if (ks + 2 < 8) {                          // depth-2 prefetch
            int nb = (ks+2) - ((ks+2)/3)*3;
            int k0 = (ks+2)*32;
            #pragma unroll
            for (int i = 0; i < 2; i++) {
                int r0 = i*64 + w*16;
                gl_lds16(&xn[(long)(m0 + r0 + srow)*DD + k0 + scb], &As[nb][r0*32]);
                gl_lds16(&Wuv_t[(long)(n0 + r0 + srow)*DD + k0 + scb], &Bs[nb][r0*32]);
            }
        }
        bf16x8 a[4], bb[4];
        #pragma unroll
        for (int mt = 0; mt < 4; mt++)
            a[mt] = *(const bf16x8*)&As[cur][GOFF(wr*64 + mt*16 + l16, quad*16)];
        #pragma unroll
        for (int nt = 0; nt < 4; nt++)
            bb[nt] = *(const bf16x8*)&Bs[cur][GOFF(wc*64 + nt*16 + l16, quad*16)];
        #pragma unroll
        for (int mt = 0; mt < 4; mt++)
            #pragma unroll
            for (int nt = 0; nt < 4; nt++)
                acc[mt][nt] = __builtin_amdgcn_mfma_f32_16x16x32_bf16(
                    a[mt], bb[nt], acc[mt][nt], 0,0,0);
    }
    #pragma unroll
    for (int mt = 0; mt < 4; mt++)
    #pragma unroll
    for (int nt = 0; nt < 4; nt++) {
        int gm0 = m0 + wr*64 + mt*16 + quad*4;        // rows gm0..gm0+3
        int ge  = n0 + wc*64 + nt*16 + l16;
        float val[4];
        #pragma unroll
        for (int r = 0; r < 4; r++) {
            float xv = acc[mt][nt][r] + b_uv[ge];
            val[r] = xv / (1.0f + __expf(-xv));        // silu
        }
        if (ge < HH) {
            #pragma unroll
            for (int r = 0; r < 4; r++)
                u[(long)(gm0 + r)*HH + ge] = f2bf(val[r]);
        } else if (ge < 2*HH) {
            int h = ge - HH;
            // vfrag addr: ((b*64+mt32)*32 + ht)*512 + lane'*8 + e
            long base = (((long)((gm0 >> 11)*64 + ((gm0 & 2047) >> 5)) * 32)
                         + (h >> 4)) * 512
                        + ((((gm0 & 31) >> 3)*16 + (h & 15)) * 8) + (gm0 & 7);
            short4 o;
            o.x = f2bf(val[0]); o.y = f2bf(val[1]);
            o.z = f2bf(val[2]); o.w = f2bf(val[3]);
            *(short4*)&vfrag[base] = o;
        } else {
            int si = ge - 2*HH;
            #pragma unroll
            for (int r = 0; r < 4; r++) {
                q[(long)(gm0 + r)*SS + si] = f2bf(val[r] * gamma[si]      + beta[si]);
                k[(long)(gm0 + r)*SS + si] = f2bf(val[r] * gamma[SS + si] + beta[SS + si]);
            }
        }
    }
}

// ---------------- K5: attention + u-gate + fused GEMM2 (v10) ----------------
// v10 = v8's PV/epilogue mapping (each v fragment loaded exactly ONCE per
// block; all 16 waves share the full P tile) + v9's full-strength XOR
// swizzles (conflicts at bank floor). v9's PV h-split is REVERTED: it
// doubled v L1 traffic (128KB/iter/CU) and cost +22%.
// Hazard structure IDENTICAL to proven v4/v7/v8 single-barrier scheme.
// LDS (shorts): ks[2][64][128] swz @0 (16384), Ps[2][64][64] swz @16384
// (8192); epilogue overlay GT[64][512] swz @0 (32768). dynamic = 65536 B.
#define KSW(pp,row,cb) (smem + ((pp)*64 + (row))*128 + \
    ((((cb) ^ (((row)&15)<<4))) >> 1))
#define PSW(pp,row,cb) (smem + 16384 + ((pp)*64 + (row))*64 + \
    ((((cb) ^ (((row)&7)<<4))) >> 1))
#define GTW(row,cb)    (smem + (row)*512 + ((((cb) ^ (((row)&15)<<4))) >> 1))

__global__ __launch_bounds__(1024, 4) void k_attn(
        const short* __restrict__ q, const short* __restrict__ k,
        const short* __restrict__ vfrag, const short* __restrict__ u,
        const short* __restrict__ Wo_t, const float* __restrict__ b_o,
        float* __restrict__ out) {
    extern __shared__ __align__(16) short smem[];
    int b = blockIdx.x & 7;                  // batch -> XCD pin
    int i0 = (blockIdx.x >> 3) * 64;
    int t = threadIdx.x, w = t >> 6, lane = t & 63;
    int l16 = lane & 15, quad = lane >> 4;
    int qt = w >> 2, mtile = w & 3;          // QK tile assignment (4x4)
    const short* qb  = q + ((long)b * NN + i0) * SS;
    const short* kb  = k + (long)b * NN * SS;
    const short* vfb = vfrag + (long)b * 64 * 32 * 512;
    const float RS = 0.08838834764831845f;   // 1/sqrt(128)

    int krow = t >> 4, kch = t & 15;         // k staging: 64 rows x 16 chunks(16B)

    // hoist q B-frags for this wave's q-tile: B[n=q=l16][k=s]
    bf16x8 qf[4];
    #pragma unroll
    for (int kc = 0; kc < 4; kc++)
        qf[kc] = *(const bf16x8*)&qb[(long)(qt*16 + l16)*SS + kc*32 + quad*8];

    // prologue: stage k rows 0..63 -> ks[0]; preload rows 64..127 -> kpre
    *(bf16x8*)KSW(0, krow, kch*16) = *(const bf16x8*)&kb[(long)krow*SS + kch*8];
    bf16x8 kpre = *(const bf16x8*)&kb[(long)(64 + krow)*SS + kch*8];
    __syncthreads();

    f32x4 acc[4][2] = {};
    for (int it = 0; it < NN/64; it++) {
        int p = it & 1;
        int m0 = it * 64;
        // preload k for m0+128 (clamp keeps address valid; value unused at end)
        int mnext = (m0 + 128 < NN) ? m0 + 128 : m0;
        bf16x8 knext = *(const bf16x8*)&kb[(long)(mnext + krow)*SS + kch*8];
        // this iter's v B-frags: coalesced 1KB global loads (land during QK);
        // each fragment loaded by exactly one wave (w*2+j covers 0..31)
        bf16x8 vf[2][2];
        #pragma unroll
        for (int s = 0; s < 2; s++)
            #pragma unroll
            for (int j = 0; j < 2; j++)
                vf[s][j] = *(const bf16x8*)
                    &vfb[((long)(it*2 + s)*32 + (w*2 + j))*512 + lane*8];
        // QK: S^T tile (16m x 16q), A = k-frags from swizzled LDS, B = q regs
        f32x4 sc = {};
        #pragma unroll
        for (int kc = 0; kc < 4; kc++) {
            bf16x8 kf = *(const bf16x8*)KSW(p, mtile*16 + l16, kc*64 + quad*16);
            sc = __builtin_amdgcn_mfma_f32_16x16x32_bf16(kf, qf[kc], sc, 0,0,0);
        }
        short4 pw;
        {
            float s0 = fmaxf(sc[0]*RS, 0.f), s1 = fmaxf(sc[1]*RS, 0.f);
            float s2 = fmaxf(sc[2]*RS, 0.f), s3 = fmaxf(sc[3]*RS, 0.f);
            pw.x = f2bf(s0*s0); pw.y = f2bf(s1*s1);
            pw.z = f2bf(s2*s2); pw.w = f2bf(s3*s3);
        }
        // C-layout: row m = quad*4+r, col q = l16 -> store P^T[q][m]
        *(short4*)PSW(p, qt*16 + l16, mtile*32 + quad*8) = pw;
        // stage k(m0+64) into the other buffer (loaded last iter, landed)
        *(bf16x8*)KSW(p^1, krow, kch*16) = kpre;
        kpre = knext;
        __syncthreads();                       // single barrier per iter
        // PV: A-frags from Ps[p] (reused over both kv-halves), B = vf in regs
        __builtin_amdgcn_s_setprio(1);
        #pragma unroll
        for (int s = 0; s < 2; s++) {
            bf16x8 af[4];
            #pragma unroll
            for (int qq = 0; qq < 4; qq++)
                af[qq] = *(const bf16x8*)PSW(p, qq*16 + l16, s*64 + quad*16);
            #pragma unroll
            for (int qq = 0; qq < 4; qq++)
                #pragma unroll
                for (int j = 0; j < 2; j++)
                    acc[qq][j] = __builtin_amdgcn_mfma_f32_16x16x32_bf16(
                        af[qq], vf[s][j], acc[qq][j], 0,0,0);
        }
        __builtin_amdgcn_s_setprio(0);
    }

    // ---- fused GEMM2 epilogue: out[64 x 256] = (u .* PV) @ Wo + b_o ----
    // acc C-layout: q = qq*16+quad*4+r, h = w*32 + j*16 + l16.
    long rowbase = (long)b * NN + i0;
    __syncthreads();                         // B1: all main-loop LDS ops dead
    #pragma unroll
    for (int qq = 0; qq < 4; qq++)
    #pragma unroll
    for (int j = 0; j < 2; j++) {
        int gh = w*32 + j*16 + l16;          // global h (each wave owns 32 cols)
        #pragma unroll
        for (int r = 0; r < 4; r++) {
            int row = qq*16 + quad*4 + r;
            float uval = bf2f(u[(rowbase + row)*HH + gh]);
            *GTW(row, 2*gh) = f2bf(acc[qq][j][r] * uval);
        }
    }
    __syncthreads();                         // B2: writes visible; reads only below
    f32x4 acc2[4] = {};
    #pragma unroll
    for (int kc = 0; kc < 16; kc++) {        // K = 512 in 32-chunks
        bf16x8 A[4];
        #pragma unroll
        for (int qq = 0; qq < 4; qq++)
            A[qq] = *(const bf16x8*)GTW(qq*16 + l16, kc*64 + quad*16);
        bf16x8 Bf = *(const bf16x8*)&Wo_t[(long)(w*16 + l16)*HH + kc*32 + quad*8];
        #pragma unroll
        for (int qq = 0; qq < 4; qq++)
            acc2[qq] = __builtin_amdgcn_mfma_f32_16x16x32_bf16(A[qq], Bf, acc2[qq], 0,0,0);
    }
    // store out + bias (fp32); wave w owns d-cols [w*16, w*16+16)
    #pragma unroll
    for (int qq = 0; qq < 4; qq++)
    #pragma unroll
    for (int r = 0; r < 4; r++) {
        long grow = rowbase + qq*16 + quad*4 + r;
        int gd = w*16 + l16;
        out[grow*DD + gd] = acc2[qq][r] + b_o[gd];
    }
}

extern "C" void kernel_launch(void* const* d_in, const int* in_sizes, int n_in,
                              void* d_out, int out_size, void* d_ws, size_t ws_size,
                              hipStream_t stream) {
    const float* x     = (const float*)d_in[0];
    const float* g     = (const float*)d_in[1];
    const float* Wuv   = (const float*)d_in[2];
    const float* b_uv  = (const float*)d_in[3];
    const float* gamma = (const float*)d_in[4];
    const float* beta  = (const float*)d_in[5];
    const float* Wo    = (const float*)d_in[6];
    const float* b_o   = (const float*)d_in[7];
    float* out = (float*)d_out;

    short* ws    = (short*)d_ws;
    short* xn    = ws;                                  // 16384*256
    short* Wuv_t = xn    + (long)16384 * 256;           // 1152*256
    short* Wo_t  = Wuv_t + (long)1152 * 256;            // 256*512
    short* u     = Wo_t  + (long)256 * 512;             // 16384*512
    short* vfrag = u     + (long)16384 * 512;           // 16384*512 (frag layout)
    short* qq    = vfrag + (long)16384 * 512;           // 16384*128
    short* kk    = qq    + (long)16384 * 128;           // 16384*128

    k_pre<<<4512, 256, 0, stream>>>(x, g, xn, Wuv, Wo, Wuv_t, Wo_t);
    k_gemm1<<<dim3(128, 9), 256, 0, stream>>>(xn, Wuv_t, b_uv, gamma, beta,
                                              u, vfrag, qq, kk);
    k_attn<<<256, 1024, 65536, stream>>>(qq, kk, vfrag, u, Wo_t, b_o, out);
}